// Round 3
// baseline (80.859 us; speedup 1.0000x reference)
//
#include <hip/hip_runtime.h>
#include <hip/hip_bf16.h>

#define B_ROWS 4096
#define DIMN 128
#define N2 8192
// z pre-scaled by sqrt(log2(e)/TEMP) so sim_mfma = sim * log2e/T directly
#define SQRT_CEXP 1.6986436f

using f32x4 = __attribute__((ext_vector_type(4))) float;

// --- 1. normalize rows, scale by sqrt(CEXP), quantize to fp8 e4m3; positives -
__global__ void normpos_k(const float* __restrict__ emb_i,
                          const float* __restrict__ emb_j,
                          unsigned short* __restrict__ zq2,   // 2 fp8 / ushort
                          float* __restrict__ pospart) {
    int w    = threadIdx.x >> 6;
    int lane = threadIdx.x & 63;
    int pair = blockIdx.x * 4 + w;          // 0..4095
    float2 a = ((const float2*)(emb_i + (size_t)pair * DIMN))[lane];
    float2 b = ((const float2*)(emb_j + (size_t)pair * DIMN))[lane];
    float sa = a.x * a.x + a.y * a.y;
    float sb = b.x * b.x + b.y * b.y;
    float dp = a.x * b.x + a.y * b.y;
    #pragma unroll
    for (int m = 32; m; m >>= 1) {
        sa += __shfl_xor(sa, m);
        sb += __shfl_xor(sb, m);
        dp += __shfl_xor(dp, m);
    }
    float ia = 1.0f / fmaxf(sqrtf(sa), 1e-12f);
    float ib = 1.0f / fmaxf(sqrtf(sb), 1e-12f);
    float fa = ia * SQRT_CEXP, fb = ib * SQRT_CEXP;
    int pka = __builtin_amdgcn_cvt_pk_fp8_f32(a.x * fa, a.y * fa, 0, false);
    int pkb = __builtin_amdgcn_cvt_pk_fp8_f32(b.x * fb, b.y * fb, 0, false);
    zq2[(size_t)pair * 64 + lane] = (unsigned short)(pka & 0xffff);
    zq2[(size_t)(pair + B_ROWS) * 64 + lane] = (unsigned short)(pkb & 0xffff);
    __shared__ float red[4];
    if (lane == 0) red[w] = dp * ia * ib;   // true cosine (unscaled)
    __syncthreads();
    if (threadIdx.x == 0)
        pospart[blockIdx.x] = red[0] + red[1] + red[2] + red[3];
}

// --- tile epilogue: ps[m][j] += sum_n exp2(acc), optional diagonal mask ------
template <bool MASK>
__device__ __forceinline__ void accum_tile(const f32x4 (&acc)[2][4],
                                           float (&ps)[2][4],
                                           int rb, int ct, int rq, int fr) {
    #pragma unroll
    for (int m = 0; m < 2; ++m)
        #pragma unroll
        for (int n = 0; n < 4; ++n)
            #pragma unroll
            for (int j = 0; j < 4; ++j) {
                float e = exp2f(acc[m][n][j]);
                if (MASK) {
                    int row = rb + m * 16 + rq + j;
                    int col = ct + n * 16 + fr;
                    if (row == col) e = 0.f;
                }
                ps[m][j] += e;
            }
}

// --- 2. row-panel Gram: block owns 32 rows, sweeps all 8192 cols -------------
// 256 blocks x 8 waves; wave w covers cols [w*1024, (w+1)*1024). A in regs.
// Row sums: reg partials -> shfl reduce -> LDS cross-wave -> plain store.
__global__ __launch_bounds__(512, 2) void gram_k(const unsigned char* __restrict__ zq,
                                                 float* __restrict__ rowsum) {
    const int lane = threadIdx.x & 63;
    const int w = threadIdx.x >> 6;          // 0..7
    const int rb = blockIdx.x * 32;          // row panel base
    const int fr = lane & 15;
    const int rq = (lane >> 4) * 4;          // C/D row group
    const int kg8 = (lane >> 4) * 8;         // byte offset of lane's k-slice

    // A panel (32 rows x 128 dims fp8) into 16 VGPRs
    long A[2][4];
    #pragma unroll
    for (int m = 0; m < 2; ++m)
        #pragma unroll
        for (int kk = 0; kk < 4; ++kk)
            A[m][kk] = *(const long*)(zq + (size_t)(rb + m * 16 + fr) * DIMN + kk * 32 + kg8);

    float ps[2][4] = {};
    const int c0 = w * 1024;
    #pragma unroll
    for (int t = 0; t < 16; ++t) {
        const int ct = c0 + t * 64;
        long Bf[4][4];
        #pragma unroll
        for (int n = 0; n < 4; ++n)
            #pragma unroll
            for (int kk = 0; kk < 4; ++kk)
                Bf[n][kk] = *(const long*)(zq + (size_t)(ct + n * 16 + fr) * DIMN + kk * 32 + kg8);
        f32x4 acc[2][4] = {};
        #pragma unroll
        for (int kk = 0; kk < 4; ++kk)
            #pragma unroll
            for (int m = 0; m < 2; ++m)
                #pragma unroll
                for (int n = 0; n < 4; ++n)
                    acc[m][n] = __builtin_amdgcn_mfma_f32_16x16x32_fp8_fp8(
                        A[m][kk], Bf[n][kk], acc[m][n], 0, 0, 0);
        // diagonal crosses this tile?
        if (ct <= rb + 31 && ct + 63 >= rb)
            accum_tile<true>(acc, ps, rb, ct, rq, fr);
        else
            accum_tile<false>(acc, ps, rb, ct, rq, fr);
    }

    // reduce over the 16 fr-lanes of each row group
    #pragma unroll
    for (int m = 0; m < 2; ++m)
        #pragma unroll
        for (int j = 0; j < 4; ++j) {
            float v = ps[m][j];
            #pragma unroll
            for (int d = 1; d < 16; d <<= 1) v += __shfl_xor(v, d);
            ps[m][j] = v;
        }
    __shared__ float red[8][32];
    if (fr == 0) {
        int g = lane >> 4;
        #pragma unroll
        for (int m = 0; m < 2; ++m)
            #pragma unroll
            for (int j = 0; j < 4; ++j)
                red[w][m * 16 + g * 4 + j] = ps[m][j];
    }
    __syncthreads();
    if (threadIdx.x < 32) {
        float s = 0.f;
        #pragma unroll
        for (int ww = 0; ww < 8; ++ww) s += red[ww][threadIdx.x];
        rowsum[rb + threadIdx.x] = s;
    }
}

// --- 3. finalize: loss = (sum log(denom) - 4*sum(pos)) / (2B*5) --------------
__global__ void finalize_k(const float* __restrict__ rowsum,
                           const float* __restrict__ pospart,
                           float* __restrict__ out) {
    float acc = 0.f;
    for (int r = threadIdx.x; r < N2; r += 256) acc += logf(rowsum[r]);
    float pp = 0.f;
    for (int r = threadIdx.x; r < 1024; r += 256) pp += pospart[r];
    acc -= 4.0f * pp;
    #pragma unroll
    for (int m = 32; m; m >>= 1) acc += __shfl_xor(acc, m);
    __shared__ float red[4];
    if ((threadIdx.x & 63) == 0) red[threadIdx.x >> 6] = acc;
    __syncthreads();
    if (threadIdx.x == 0)
        out[0] = (red[0] + red[1] + red[2] + red[3]) / (float)(2 * B_ROWS * 5);
}

extern "C" void kernel_launch(void* const* d_in, const int* in_sizes, int n_in,
                              void* d_out, int out_size, void* d_ws, size_t ws_size,
                              hipStream_t stream) {
    const float* emb_i = (const float*)d_in[0];
    const float* emb_j = (const float*)d_in[1];
    unsigned char* zq = (unsigned char*)d_ws;                     // 1 MB fp8 Z
    float* rowsum  = (float*)((char*)d_ws + (size_t)N2 * DIMN);   // 32 KB
    float* pospart = rowsum + N2;                                 // 4 KB

    normpos_k<<<1024, 256, 0, stream>>>(emb_i, emb_j, (unsigned short*)zq, pospart);
    gram_k<<<256, 512, 0, stream>>>(zq, rowsum);
    finalize_k<<<1, 256, 0, stream>>>(rowsum, pospart, (float*)d_out);
}

// Round 4
// 46.299 us; speedup vs baseline: 1.7465x; 1.7465x over previous
//
#include <hip/hip_runtime.h>
#include <hip/hip_bf16.h>

#define B_ROWS 4096
#define DIMN 128
#define N2 8192
// z pre-scaled by sqrt(log2(e)/TEMP) so mfma output is already the exp2 arg
#define SQRT_CEXP 1.6986436f

using f32x4 = __attribute__((ext_vector_type(4))) float;
typedef long i64;

// Tiled fp8 Z layout: 8-byte chunk index = (R*4 + kk)*64 + g*16 + fr
//   R = row/16, fr = row%16, kk = k-block (32 fp8 each), g = 8-byte sub-slice.
// A wave's MFMA fragment load (lane = g*16+fr) is then zt[(R*4+kk)*64 + lane]
// -> 512B contiguous per instruction, perfectly coalesced.

// --- 1. normalize+scale+quantize into tiled layout; positives partials ------
// 256 blocks x 256 threads; block owns pairs [b*16, b*16+16) = full 16-row
// tiles R=b (i-side) and R=256+b (j-side). Thread t: row lr=t/16, dims s*8..+7.
__global__ __launch_bounds__(256) void normpos_k(const float* __restrict__ emb_i,
                                                 const float* __restrict__ emb_j,
                                                 i64* __restrict__ zt,
                                                 float* __restrict__ pospart) {
    const int t = threadIdx.x;
    const int lr = t >> 4;          // local row / pair
    const int s  = t & 15;          // 8-dim slice
    const int p  = blockIdx.x * 16 + lr;
    const float4* ai = (const float4*)(emb_i + (size_t)p * DIMN + s * 8);
    const float4* bj = (const float4*)(emb_j + (size_t)p * DIMN + s * 8);
    float4 a0 = ai[0], a1 = ai[1];
    float4 b0 = bj[0], b1 = bj[1];
    float sa = a0.x*a0.x + a0.y*a0.y + a0.z*a0.z + a0.w*a0.w
             + a1.x*a1.x + a1.y*a1.y + a1.z*a1.z + a1.w*a1.w;
    float sb = b0.x*b0.x + b0.y*b0.y + b0.z*b0.z + b0.w*b0.w
             + b1.x*b1.x + b1.y*b1.y + b1.z*b1.z + b1.w*b1.w;
    float dp = a0.x*b0.x + a0.y*b0.y + a0.z*b0.z + a0.w*b0.w
             + a1.x*b1.x + a1.y*b1.y + a1.z*b1.z + a1.w*b1.w;
    #pragma unroll
    for (int d = 1; d < 16; d <<= 1) {   // reduce within 16-lane row group
        sa += __shfl_xor(sa, d);
        sb += __shfl_xor(sb, d);
        dp += __shfl_xor(dp, d);
    }
    float ia = 1.0f / fmaxf(sqrtf(sa), 1e-12f);
    float ib = 1.0f / fmaxf(sqrtf(sb), 1e-12f);
    float fa = ia * SQRT_CEXP, fb = ib * SQRT_CEXP;

    int wa0 = __builtin_amdgcn_cvt_pk_fp8_f32(a0.x * fa, a0.y * fa, 0, false);
    wa0     = __builtin_amdgcn_cvt_pk_fp8_f32(a0.z * fa, a0.w * fa, wa0, true);
    int wa1 = __builtin_amdgcn_cvt_pk_fp8_f32(a1.x * fa, a1.y * fa, 0, false);
    wa1     = __builtin_amdgcn_cvt_pk_fp8_f32(a1.z * fa, a1.w * fa, wa1, true);
    i64 qa = ((i64)(unsigned)wa1 << 32) | (unsigned)wa0;
    int wb0 = __builtin_amdgcn_cvt_pk_fp8_f32(b0.x * fb, b0.y * fb, 0, false);
    wb0     = __builtin_amdgcn_cvt_pk_fp8_f32(b0.z * fb, b0.w * fb, wb0, true);
    int wb1 = __builtin_amdgcn_cvt_pk_fp8_f32(b1.x * fb, b1.y * fb, 0, false);
    wb1     = __builtin_amdgcn_cvt_pk_fp8_f32(b1.z * fb, b1.w * fb, wb1, true);
    i64 qb = ((i64)(unsigned)wb1 << 32) | (unsigned)wb0;

    const int kk = s >> 2, g = s & 3;
    zt[((blockIdx.x * 4 + kk) * 64) + g * 16 + lr] = qa;                 // R = b
    zt[(((256 + blockIdx.x) * 4 + kk) * 64) + g * 16 + lr] = qb;         // R = 256+b

    __shared__ float red[16];
    if (s == 0) red[lr] = dp * ia * ib;
    __syncthreads();
    if (t == 0) {
        float x = 0.f;
        #pragma unroll
        for (int i = 0; i < 16; ++i) x += red[i];
        pospart[blockIdx.x] = x;
    }
}

// --- tile epilogue: ps[m][j] += sum_n exp2(acc), optional diagonal mask ------
template <bool MASK>
__device__ __forceinline__ void accum_tile(const f32x4 (&acc)[4][4],
                                           float (&ps)[4][4],
                                           int rb, int ct, int rq, int fr) {
    #pragma unroll
    for (int m = 0; m < 4; ++m)
        #pragma unroll
        for (int n = 0; n < 4; ++n)
            #pragma unroll
            for (int j = 0; j < 4; ++j) {
                float e = exp2f(acc[m][n][j]);
                if (MASK) {
                    if (rb + m * 16 + rq + j == ct + n * 16 + fr) e = 0.f;
                }
                ps[m][j] += e;
            }
}

// --- 2. row-panel Gram: block owns 64 rows x one 4096-col half ---------------
// 256 blocks x 512 threads; block b: rows (b>>1)*64, col half b&1.
// Wave w sweeps cols h*4096 + w*512 .. +512 (8 tiles of 64).
__global__ __launch_bounds__(512, 2) void gram_k(const i64* __restrict__ zt,
                                                 float* __restrict__ rowpart) {
    const int lane = threadIdx.x & 63;
    const int w = threadIdx.x >> 6;
    const int rb = (blockIdx.x >> 1) * 64;
    const int h  = blockIdx.x & 1;
    const int fr = lane & 15;
    const int rq = (lane >> 4) * 4;

    i64 A[4][4];
    #pragma unroll
    for (int m = 0; m < 4; ++m)
        #pragma unroll
        for (int kk = 0; kk < 4; ++kk)
            A[m][kk] = zt[((rb / 16 + m) * 4 + kk) * 64 + lane];

    float ps[4][4] = {};
    const int c0 = h * 4096 + w * 512;
    for (int tt = 0; tt < 8; ++tt) {
        const int ct = c0 + tt * 64;
        i64 Bf[4][4];
        #pragma unroll
        for (int n = 0; n < 4; ++n)
            #pragma unroll
            for (int kk = 0; kk < 4; ++kk)
                Bf[n][kk] = zt[((ct / 16 + n) * 4 + kk) * 64 + lane];
        f32x4 acc[4][4] = {};
        #pragma unroll
        for (int kk = 0; kk < 4; ++kk)
            #pragma unroll
            for (int m = 0; m < 4; ++m)
                #pragma unroll
                for (int n = 0; n < 4; ++n)
                    acc[m][n] = __builtin_amdgcn_mfma_f32_16x16x32_fp8_fp8(
                        A[m][kk], Bf[n][kk], acc[m][n], 0, 0, 0);
        if (ct == rb) accum_tile<true>(acc, ps, rb, ct, rq, fr);
        else         accum_tile<false>(acc, ps, rb, ct, rq, fr);
    }

    // 16-lane reduce per row, cross-wave LDS reduce, plain store
    #pragma unroll
    for (int m = 0; m < 4; ++m)
        #pragma unroll
        for (int j = 0; j < 4; ++j) {
            float v = ps[m][j];
            #pragma unroll
            for (int d = 1; d < 16; d <<= 1) v += __shfl_xor(v, d);
            ps[m][j] = v;
        }
    __shared__ float red[8][64];
    if (fr == 0) {
        #pragma unroll
        for (int m = 0; m < 4; ++m)
            #pragma unroll
            for (int j = 0; j < 4; ++j)
                red[w][m * 16 + rq + j] = ps[m][j];
    }
    __syncthreads();
    if (threadIdx.x < 64) {
        float ssum = 0.f;
        #pragma unroll
        for (int ww = 0; ww < 8; ++ww) ssum += red[ww][threadIdx.x];
        rowpart[h * N2 + rb + threadIdx.x] = ssum;
    }
}

// --- 3. finalize: loss = (sum log(denom) - 4*sum(pos)) / (2B*5) --------------
__global__ void finalize_k(const float* __restrict__ rowpart,
                           const float* __restrict__ pospart,
                           float* __restrict__ out) {
    float acc = 0.f;
    for (int r = threadIdx.x; r < N2; r += 256)
        acc += logf(rowpart[r] + rowpart[N2 + r]);
    if (threadIdx.x < 256) acc -= 4.0f * pospart[threadIdx.x];
    #pragma unroll
    for (int m = 32; m; m >>= 1) acc += __shfl_xor(acc, m);
    __shared__ float red[4];
    if ((threadIdx.x & 63) == 0) red[threadIdx.x >> 6] = acc;
    __syncthreads();
    if (threadIdx.x == 0)
        out[0] = (red[0] + red[1] + red[2] + red[3]) / (float)(2 * B_ROWS * 5);
}

extern "C" void kernel_launch(void* const* d_in, const int* in_sizes, int n_in,
                              void* d_out, int out_size, void* d_ws, size_t ws_size,
                              hipStream_t stream) {
    const float* emb_i = (const float*)d_in[0];
    const float* emb_j = (const float*)d_in[1];
    i64* zt        = (i64*)d_ws;                                   // 1 MB tiled fp8
    float* rowpart = (float*)((char*)d_ws + (size_t)N2 * DIMN);    // 64 KB (2 halves)
    float* pospart = rowpart + 2 * N2;                             // 1 KB

    normpos_k<<<256, 256, 0, stream>>>(emb_i, emb_j, zt, pospart);
    gram_k<<<256, 512, 0, stream>>>(zt, rowpart);
    finalize_k<<<1, 256, 0, stream>>>(rowpart, pospart, (float*)d_out);
}

// Round 5
// 37.054 us; speedup vs baseline: 2.1822x; 1.2495x over previous
//
#include <hip/hip_runtime.h>
#include <hip/hip_bf16.h>

#define B_ROWS 4096
#define DIMN 128
#define N2 8192
// z pre-scaled by sqrt(log2(e)/TEMP) so mfma output is already the exp2 arg
#define SQRT_CEXP 1.6986436f

using f32x4 = __attribute__((ext_vector_type(4))) float;
typedef long i64;

// Tiled fp8 Z layout: 8-byte chunk index = (R*4 + kk)*64 + g*16 + fr
//   R = row/16, fr = row%16, kk = k-block (32 fp8 each), g = 8-byte sub-slice.
// A wave's MFMA fragment load (lane = g*16+fr) is zt[(R*4+kk)*64 + lane]
// -> 512B contiguous per instruction, perfectly coalesced.

// --- 1. normalize+scale+quantize into tiled layout; positives partials ------
__global__ __launch_bounds__(256) void normpos_k(const float* __restrict__ emb_i,
                                                 const float* __restrict__ emb_j,
                                                 i64* __restrict__ zt,
                                                 float* __restrict__ pospart) {
    const int t = threadIdx.x;
    const int lr = t >> 4;          // local row / pair
    const int s  = t & 15;          // 8-dim slice
    const int p  = blockIdx.x * 16 + lr;
    const float4* ai = (const float4*)(emb_i + (size_t)p * DIMN + s * 8);
    const float4* bj = (const float4*)(emb_j + (size_t)p * DIMN + s * 8);
    float4 a0 = ai[0], a1 = ai[1];
    float4 b0 = bj[0], b1 = bj[1];
    float sa = a0.x*a0.x + a0.y*a0.y + a0.z*a0.z + a0.w*a0.w
             + a1.x*a1.x + a1.y*a1.y + a1.z*a1.z + a1.w*a1.w;
    float sb = b0.x*b0.x + b0.y*b0.y + b0.z*b0.z + b0.w*b0.w
             + b1.x*b1.x + b1.y*b1.y + b1.z*b1.z + b1.w*b1.w;
    float dp = a0.x*b0.x + a0.y*b0.y + a0.z*b0.z + a0.w*b0.w
             + a1.x*b1.x + a1.y*b1.y + a1.z*b1.z + a1.w*b1.w;
    #pragma unroll
    for (int d = 1; d < 16; d <<= 1) {
        sa += __shfl_xor(sa, d);
        sb += __shfl_xor(sb, d);
        dp += __shfl_xor(dp, d);
    }
    float ia = 1.0f / fmaxf(sqrtf(sa), 1e-12f);
    float ib = 1.0f / fmaxf(sqrtf(sb), 1e-12f);
    float fa = ia * SQRT_CEXP, fb = ib * SQRT_CEXP;

    int wa0 = __builtin_amdgcn_cvt_pk_fp8_f32(a0.x * fa, a0.y * fa, 0, false);
    wa0     = __builtin_amdgcn_cvt_pk_fp8_f32(a0.z * fa, a0.w * fa, wa0, true);
    int wa1 = __builtin_amdgcn_cvt_pk_fp8_f32(a1.x * fa, a1.y * fa, 0, false);
    wa1     = __builtin_amdgcn_cvt_pk_fp8_f32(a1.z * fa, a1.w * fa, wa1, true);
    i64 qa = ((i64)(unsigned)wa1 << 32) | (unsigned)wa0;
    int wb0 = __builtin_amdgcn_cvt_pk_fp8_f32(b0.x * fb, b0.y * fb, 0, false);
    wb0     = __builtin_amdgcn_cvt_pk_fp8_f32(b0.z * fb, b0.w * fb, wb0, true);
    int wb1 = __builtin_amdgcn_cvt_pk_fp8_f32(b1.x * fb, b1.y * fb, 0, false);
    wb1     = __builtin_amdgcn_cvt_pk_fp8_f32(b1.z * fb, b1.w * fb, wb1, true);
    i64 qb = ((i64)(unsigned)wb1 << 32) | (unsigned)wb0;

    const int kk = s >> 2, g = s & 3;
    zt[((blockIdx.x * 4 + kk) * 64) + g * 16 + lr] = qa;                 // R = b
    zt[(((256 + blockIdx.x) * 4 + kk) * 64) + g * 16 + lr] = qb;         // R = 256+b

    __shared__ float red[16];
    if (s == 0) red[lr] = dp * ia * ib;
    __syncthreads();
    if (t == 0) {
        float x = 0.f;
        #pragma unroll
        for (int i = 0; i < 16; ++i) x += red[i];
        pospart[blockIdx.x] = x;
    }
}

// --- half-tile compute: 32 MFMAs on a 64x32 sub-tile + exp2 epilogue ---------
template <bool MASK>
__device__ __forceinline__ void compute_half(const i64 (&A)[4][4],
                                             const i64 (&Bh)[2][4],
                                             float (&ps)[4][4],
                                             int rb, int colbase, int rq, int fr) {
    f32x4 acc[4][2] = {};
    #pragma unroll
    for (int kk = 0; kk < 4; ++kk)
        #pragma unroll
        for (int m = 0; m < 4; ++m)
            #pragma unroll
            for (int n = 0; n < 2; ++n)
                acc[m][n] = __builtin_amdgcn_mfma_f32_16x16x32_fp8_fp8(
                    A[m][kk], Bh[n][kk], acc[m][n], 0, 0, 0);
    #pragma unroll
    for (int m = 0; m < 4; ++m)
        #pragma unroll
        for (int n = 0; n < 2; ++n)
            #pragma unroll
            for (int j = 0; j < 4; ++j) {
                float e = exp2f(acc[m][n][j]);
                if (MASK) {
                    if (rb + m * 16 + rq + j == colbase + n * 16 + fr) e = 0.f;
                }
                ps[m][j] += e;
            }
}

// --- 2. row-panel Gram: block owns 64 rows x one 2048-col quarter ------------
// 512 blocks x 512 threads (2 blocks/CU); block b: panel b>>2, quarter b&3.
// Wave w sweeps cols q*2048 + w*256 .. +256 = 8 half-tiles of 64x32,
// software-pipelined with a static double buffer.
__global__ __launch_bounds__(512, 4) void gram_k(const i64* __restrict__ zt,
                                                 float* __restrict__ rowpart) {
    const int lane = threadIdx.x & 63;
    const int w = threadIdx.x >> 6;
    const int rb = (blockIdx.x >> 2) * 64;
    const int q  = blockIdx.x & 3;
    const int fr = lane & 15;
    const int rq = (lane >> 4) * 4;

    const i64* Ab = zt + ((size_t)(rb >> 4) << 8) + lane;
    i64 A[4][4];
    #pragma unroll
    for (int m = 0; m < 4; ++m)
        #pragma unroll
        for (int kk = 0; kk < 4; ++kk)
            A[m][kk] = Ab[m * 256 + kk * 64];

    const int c0 = q * 2048 + w * 256;
    const i64* Bb = zt + ((size_t)(c0 >> 4) << 8) + lane;

    float ps[4][4] = {};
    i64 Bh[2][2][4];
    #pragma unroll
    for (int n = 0; n < 2; ++n)
        #pragma unroll
        for (int kk = 0; kk < 4; ++kk)
            Bh[0][n][kk] = Bb[n * 256 + kk * 64];

    #pragma unroll
    for (int hs = 0; hs < 8; ++hs) {
        const int cur = hs & 1;
        if (hs < 7) {
            #pragma unroll
            for (int n = 0; n < 2; ++n)
                #pragma unroll
                for (int kk = 0; kk < 4; ++kk)
                    Bh[cur ^ 1][n][kk] = Bb[((hs + 1) * 2 + n) * 256 + kk * 64];
        }
        const int ct = c0 + (hs >> 1) * 64;           // 64-tile base
        const int colbase = ct + (hs & 1) * 32;       // this half's col base
        if (ct == rb) compute_half<true >(A, Bh[cur], ps, rb, colbase, rq, fr);
        else          compute_half<false>(A, Bh[cur], ps, rb, colbase, rq, fr);
    }

    // 16-lane reduce per row, cross-wave LDS reduce, plain store
    #pragma unroll
    for (int m = 0; m < 4; ++m)
        #pragma unroll
        for (int j = 0; j < 4; ++j) {
            float v = ps[m][j];
            #pragma unroll
            for (int d = 1; d < 16; d <<= 1) v += __shfl_xor(v, d);
            ps[m][j] = v;
        }
    __shared__ float red[8][64];
    if (fr == 0) {
        #pragma unroll
        for (int m = 0; m < 4; ++m)
            #pragma unroll
            for (int j = 0; j < 4; ++j)
                red[w][m * 16 + rq + j] = ps[m][j];
    }
    __syncthreads();
    if (threadIdx.x < 64) {
        float ssum = 0.f;
        #pragma unroll
        for (int ww = 0; ww < 8; ++ww) ssum += red[ww][threadIdx.x];
        rowpart[q * N2 + rb + threadIdx.x] = ssum;
    }
}

// --- 3. finalize: loss = (sum log(denom) - 4*sum(pos)) / (2B*5) --------------
__global__ void finalize_k(const float* __restrict__ rowpart,
                           const float* __restrict__ pospart,
                           float* __restrict__ out) {
    const int t = threadIdx.x;
    float acc = 0.f;
    for (int r = t; r < N2; r += 1024)
        acc += log2f(rowpart[r] + rowpart[N2 + r] + rowpart[2 * N2 + r] + rowpart[3 * N2 + r]);
    acc *= 0.6931471805599453f;
    if (t < 256) acc -= 4.0f * pospart[t];
    #pragma unroll
    for (int m = 32; m; m >>= 1) acc += __shfl_xor(acc, m);
    __shared__ float red[16];
    if ((t & 63) == 0) red[t >> 6] = acc;
    __syncthreads();
    if (t == 0) {
        float x = 0.f;
        #pragma unroll
        for (int i = 0; i < 16; ++i) x += red[i];
        out[0] = x / (float)(2 * B_ROWS * 5);
    }
}

extern "C" void kernel_launch(void* const* d_in, const int* in_sizes, int n_in,
                              void* d_out, int out_size, void* d_ws, size_t ws_size,
                              hipStream_t stream) {
    const float* emb_i = (const float*)d_in[0];
    const float* emb_j = (const float*)d_in[1];
    i64* zt        = (i64*)d_ws;                                   // 1 MB tiled fp8
    float* rowpart = (float*)((char*)d_ws + (size_t)N2 * DIMN);    // 128 KB (4 parts)
    float* pospart = rowpart + 4 * N2;                             // 1 KB

    normpos_k<<<256, 256, 0, stream>>>(emb_i, emb_j, zt, pospart);
    gram_k<<<512, 512, 0, stream>>>(zt, rowpart);
    finalize_k<<<1, 1024, 0, stream>>>(rowpart, pospart, (float*)d_out);
}